// Round 2
// baseline (1791.332 us; speedup 1.0000x reference)
//
#include <hip/hip_runtime.h>
#include <hip/hip_bf16.h>

#define NN 100000
#define NE 1600000
#define INF 32
#define OUTF 64

typedef __hip_bfloat16 bf16;

__device__ __forceinline__ float b2f(bf16 v) { return __bfloat162float(v); }

__device__ __forceinline__ float load_f(const void* p, long long i, int f32) {
  return f32 ? ((const float*)p)[i] : __bfloat162float(((const bf16*)p)[i]);
}
__device__ __forceinline__ int load_idx(const void* p, long long i, int i64) {
  return i64 ? (int)((const long long*)p)[i] : ((const int*)p)[i];
}

// ---- kernel 0: dtype detector (1 block, 64 threads) ----
__global__ void k_detect(const void* __restrict__ x, const void* __restrict__ ei,
                         int* __restrict__ flags)
{
  int t = threadIdx.x;
  const unsigned* xu = (const unsigned*)x;
  int hits = 0;
  #pragma unroll
  for (int i = 0; i < 16; ++i) {
    unsigned w = xu[t * 16 + i];
    unsigned mid = (w >> 7) & 0xFF;           // lo-half bf16 exponent field if packed bf16
    hits += (mid >= 0x70 && mid <= 0x86) ? 1 : 0;
  }
  #pragma unroll
  for (int off = 32; off > 0; off >>= 1) hits += __shfl_xor(hits, off, 64);
  const int* e32 = (const int*)ei;
  unsigned long long m = __ballot(e32[2 * t + 1] == 0);  // int64 high words all zero?
  if (t == 0) {
    flags[0] = (hits < 512) ? 1 : 0;   // 1 => floats are f32 (mid-bits uniform)
    flags[1] = (m == ~0ULL) ? 1 : 0;   // 1 => edge_index is int64
  }
}

// ---- kernel 1: mean-aggregation scatter (f32 atomics into ws) ----
__global__ __launch_bounds__(256)
void k_agg(const void* __restrict__ x, const void* __restrict__ ei,
           float* __restrict__ agg, float* __restrict__ cnt,
           const int* __restrict__ flags)
{
  int xf32 = flags[0], ei64 = flags[1];
  long long gid = (long long)blockIdx.x * 256 + threadIdx.x;
  int e = (int)(gid >> 5);
  int f = (int)(gid & 31);
  int src = load_idx(ei, e, ei64);
  int dst = load_idx(ei, (long long)NE + e, ei64);
  atomicAdd(&agg[(long long)dst * INF + f], load_f(x, (long long)src * INF + f, xf32));
  if (f == 0) atomicAdd(&cnt[dst], 1.0f);
}

// ---- kernel 2: h = tanh(mean_agg @ W_l + b_l + x @ W_r), h stored bf16 ALIASED over agg ----
__global__ __launch_bounds__(256)
void k_node(const void* __restrict__ x, float* __restrict__ agg,
            const float* __restrict__ cnt,
            const void* __restrict__ Wl, const void* __restrict__ Wr,
            const void* __restrict__ bl, const int* __restrict__ flags)
{
  __shared__ float4 sWl[8 * 64];   // [k4][t]: W_l[4k4+j][t] in comp j
  __shared__ float4 sWr[8 * 64];
  __shared__ float sx[4][32];
  __shared__ float sa[4][32];
  int xf32 = flags[0];
  int tid = threadIdx.x;
  for (int i = tid; i < INF * OUTF; i += 256) {
    int k = i >> 6, t = i & 63;
    ((float*)sWl)[((k >> 2) * 64 + t) * 4 + (k & 3)] = load_f(Wl, i, xf32);
    ((float*)sWr)[((k >> 2) * 64 + t) * 4 + (k & 3)] = load_f(Wr, i, xf32);
  }
  int nl = tid >> 6;
  int t = tid & 63;
  int node = blockIdx.x * 4 + nl;
  if (t < 32) {
    sx[nl][t] = load_f(x, (long long)node * INF + t, xf32);
  } else {
    int k = t - 32;
    sa[nl][k] = agg[node * INF + k] / fmaxf(cnt[node], 1.0f);
  }
  __syncthreads();   // all agg reads for this block's 4 nodes complete before overwrite
  float acc = load_f(bl, t, xf32);
  #pragma unroll
  for (int k4 = 0; k4 < 8; ++k4) {
    float4 wl = sWl[k4 * 64 + t];
    float4 wr = sWr[k4 * 64 + t];
    float4 a4 = *(const float4*)&sa[nl][k4 * 4];
    float4 x4 = *(const float4*)&sx[nl][k4 * 4];
    acc += a4.x * wl.x + a4.y * wl.y + a4.z * wl.z + a4.w * wl.w;
    acc += x4.x * wr.x + x4.y * wr.y + x4.z * wr.z + x4.w * wr.w;
  }
  bf16* h = (bf16*)agg;            // aliased: node's 128B agg slot becomes 64x bf16 h slot
  h[(long long)node * OUTF + t] = __float2bfloat16(tanhf(acc));
}

// ---- kernel 3: per-edge MLP. One wave handles 8 edges; lane = out feature ----
__global__ __launch_bounds__(256)
void k_edge(const bf16* __restrict__ h, const void* __restrict__ ei,
            const void* __restrict__ W1, const void* __restrict__ b1,
            const void* __restrict__ W2, const void* __restrict__ b2,
            void* __restrict__ outv, const int* __restrict__ flags)
{
  __shared__ float4 sW1[32 * 64];     // 32 KiB, [k4][t]: W1[4k4+j][t] in comp j
  __shared__ float she[4][128][8];    // 16 KiB, [wave][k][edge] (reads are broadcast)
  int xf32 = flags[0], ei64 = flags[1];
  int tid = threadIdx.x;
  int lane = tid & 63;
  int wv = tid >> 6;

  for (int i = tid; i < 128 * 64; i += 256) {
    int k = i >> 6, t = i & 63;
    ((float*)sW1)[((k >> 2) * 64 + t) * 4 + (k & 3)] = load_f(W1, i, xf32);
  }

  int e0 = blockIdx.x * 32 + wv * 8;
  #pragma unroll
  for (int j = 0; j < 16; ++j) {        // 8 edges x 2 halves (src/dst rows)
    int e = j >> 1;
    int half = j & 1;
    int node = load_idx(ei, (long long)(half ? NE : 0) + e0 + e, ei64);
    she[wv][half * 64 + lane][e] = b2f(h[(long long)node * OUTF + lane]);
  }
  __syncthreads();

  float acc[8];
  float bb = load_f(b1, lane, xf32);
  #pragma unroll
  for (int e = 0; e < 8; ++e) acc[e] = bb;

  #pragma unroll 4
  for (int k4 = 0; k4 < 32; ++k4) {
    float4 w = sW1[k4 * 64 + lane];
    #pragma unroll
    for (int j = 0; j < 4; ++j) {
      float wj = j == 0 ? w.x : j == 1 ? w.y : j == 2 ? w.z : w.w;
      const float* p = &she[wv][k4 * 4 + j][0];
      float4 ha = *(const float4*)p;
      float4 hb = *(const float4*)(p + 4);
      acc[0] += ha.x * wj; acc[1] += ha.y * wj;
      acc[2] += ha.z * wj; acc[3] += ha.w * wj;
      acc[4] += hb.x * wj; acc[5] += hb.y * wj;
      acc[6] += hb.z * wj; acc[7] += hb.w * wj;
    }
  }

  // layer 2: z_e = sum_t tanh(acc_e[t]) * W2[t]; then tanh, sigmoid
  float w2 = load_f(W2, lane, xf32);
  float b2v = load_f(b2, 0, xf32);
  float zs[8];
  #pragma unroll
  for (int e = 0; e < 8; ++e) {
    float z = tanhf(acc[e]) * w2;
    #pragma unroll
    for (int off = 32; off > 0; off >>= 1)
      z += __shfl_xor(z, off, 64);
    zs[e] = z;
  }
  float zz = zs[0];
  #pragma unroll
  for (int e = 1; e < 8; ++e) zz = (lane == e) ? zs[e] : zz;
  if (lane < 8) {
    float y = tanhf(zz + b2v);
    float r = 1.0f / (1.0f + expf(-y));
    if (xf32) ((float*)outv)[e0 + lane] = r;
    else      ((bf16*)outv)[e0 + lane] = __float2bfloat16(r);
  }
}

extern "C" void kernel_launch(void* const* d_in, const int* in_sizes, int n_in,
                              void* d_out, int out_size, void* d_ws, size_t ws_size,
                              hipStream_t stream)
{
  const void* x  = d_in[0];
  const void* ei = d_in[1];
  const void* Wl = d_in[2];
  const void* Wr = d_in[3];
  const void* bl = d_in[4];
  const void* W1 = d_in[5];
  const void* b1 = d_in[6];
  const void* W2 = d_in[7];
  const void* b2 = d_in[8];

  char* ws = (char*)d_ws;
  float* agg = (float*)ws;                                  // NN*32 f32 = 12.8 MB (later aliased as bf16 h)
  float* cnt = (float*)(ws + (size_t)NN * INF * 4);         // NN f32 = 0.4 MB
  int* flags = (int*)(ws + (size_t)NN * INF * 4 + (size_t)NN * 4);

  k_detect<<<1, 64, 0, stream>>>(x, ei, flags);
  hipMemsetAsync(agg, 0, (size_t)NN * INF * 4 + (size_t)NN * 4, stream);

  k_agg<<<(NE * 32) / 256, 256, 0, stream>>>(x, ei, agg, cnt, flags);
  k_node<<<NN / 4, 256, 0, stream>>>(x, agg, cnt, Wl, Wr, bl, flags);
  k_edge<<<NE / 32, 256, 0, stream>>>((const bf16*)agg, ei, W1, b1, W2, b2, d_out, flags);
}

// Round 3
// 592.906 us; speedup vs baseline: 3.0213x; 3.0213x over previous
//
#include <hip/hip_runtime.h>
#include <hip/hip_bf16.h>

#define NN 100000
#define NE 1600000
#define INF 32
#define OUTF 64

typedef __hip_bfloat16 bf16;
typedef __attribute__((ext_vector_type(8))) short short8v;
typedef __attribute__((ext_vector_type(4))) float float4v;

__device__ __forceinline__ float b2f(bf16 v) { return __bfloat162float(v); }

__device__ __forceinline__ float load_f(const void* p, long long i, int f32) {
  return f32 ? ((const float*)p)[i] : __bfloat162float(((const bf16*)p)[i]);
}
__device__ __forceinline__ int load_idx(const void* p, long long i, int i64) {
  return i64 ? (int)((const long long*)p)[i] : ((const int*)p)[i];
}
__device__ __forceinline__ float fast_tanh(float x) {
  float e = __expf(2.0f * x);                      // v_mul + v_exp
  return 1.0f - 2.0f * __builtin_amdgcn_rcpf(e + 1.0f);
}

// ---- kernel 0: dtype detector (1 block, 64 threads) ----
__global__ void k_detect(const void* __restrict__ x, const void* __restrict__ ei,
                         int* __restrict__ flags)
{
  int t = threadIdx.x;
  const unsigned* xu = (const unsigned*)x;
  int hits = 0;
  #pragma unroll
  for (int i = 0; i < 16; ++i) {
    unsigned w = xu[t * 16 + i];
    unsigned mid = (w >> 7) & 0xFF;           // lo-half bf16 exponent field if packed bf16
    hits += (mid >= 0x70 && mid <= 0x86) ? 1 : 0;
  }
  #pragma unroll
  for (int off = 32; off > 0; off >>= 1) hits += __shfl_xor(hits, off, 64);
  const int* e32 = (const int*)ei;
  unsigned long long m = __ballot(e32[2 * t + 1] == 0);  // int64 high words all zero?
  if (t == 0) {
    flags[0] = (hits < 512) ? 1 : 0;   // 1 => floats are f32 (mid-bits uniform)
    flags[1] = (m == ~0ULL) ? 1 : 0;   // 1 => edge_index is int64
  }
}

// ---- kernel 1: mean-aggregation scatter (f32 atomics into ws) ----
__global__ __launch_bounds__(256)
void k_agg(const void* __restrict__ x, const void* __restrict__ ei,
           float* __restrict__ agg, float* __restrict__ cnt,
           const int* __restrict__ flags)
{
  int xf32 = flags[0], ei64 = flags[1];
  long long gid = (long long)blockIdx.x * 256 + threadIdx.x;
  int e = (int)(gid >> 5);
  int f = (int)(gid & 31);
  int src = load_idx(ei, e, ei64);
  int dst = load_idx(ei, (long long)NE + e, ei64);
  atomicAdd(&agg[(long long)dst * INF + f], load_f(x, (long long)src * INF + f, xf32));
  if (f == 0) atomicAdd(&cnt[dst], 1.0f);
}

// ---- kernel 2: h = tanh(mean_agg @ W_l + b_l + x @ W_r), h stored bf16 ALIASED over agg ----
__global__ __launch_bounds__(256)
void k_node(const void* __restrict__ x, float* __restrict__ agg,
            const float* __restrict__ cnt,
            const void* __restrict__ Wl, const void* __restrict__ Wr,
            const void* __restrict__ bl, const int* __restrict__ flags)
{
  __shared__ float4 sWl[8 * 64];   // [k4][t]: W_l[4k4+j][t] in comp j
  __shared__ float4 sWr[8 * 64];
  __shared__ float sx[4][32];
  __shared__ float sa[4][32];
  int xf32 = flags[0];
  int tid = threadIdx.x;
  for (int i = tid; i < INF * OUTF; i += 256) {
    int k = i >> 6, t = i & 63;
    ((float*)sWl)[((k >> 2) * 64 + t) * 4 + (k & 3)] = load_f(Wl, i, xf32);
    ((float*)sWr)[((k >> 2) * 64 + t) * 4 + (k & 3)] = load_f(Wr, i, xf32);
  }
  int nl = tid >> 6;
  int t = tid & 63;
  int node = blockIdx.x * 4 + nl;
  if (t < 32) {
    sx[nl][t] = load_f(x, (long long)node * INF + t, xf32);
  } else {
    int k = t - 32;
    sa[nl][k] = agg[node * INF + k] / fmaxf(cnt[node], 1.0f);
  }
  __syncthreads();   // all agg reads for this block's 4 nodes complete before overwrite
  float acc = load_f(bl, t, xf32);
  #pragma unroll
  for (int k4 = 0; k4 < 8; ++k4) {
    float4 wl = sWl[k4 * 64 + t];
    float4 wr = sWr[k4 * 64 + t];
    float4 a4 = *(const float4*)&sa[nl][k4 * 4];
    float4 x4 = *(const float4*)&sx[nl][k4 * 4];
    acc += a4.x * wl.x + a4.y * wl.y + a4.z * wl.z + a4.w * wl.w;
    acc += x4.x * wr.x + x4.y * wr.y + x4.z * wr.z + x4.w * wr.w;
  }
  bf16* h = (bf16*)agg;            // aliased: node's 128B agg slot becomes 64x bf16 h slot
  h[(long long)node * OUTF + t] = __float2bfloat16(tanhf(acc));
}

// ---- kernel 3: per-edge MLP via MFMA. One wave = 16 edges per tile, grid-stride ----
// A (16 edges x 32 k): lane holds row=lane&15, k = 8*(lane>>4)+e  (contiguous 16B from h)
// B (32 k x 16 outf):  lane holds col=lane&15, k = 8*(lane>>4)+e  (W1 gathered to regs once)
// D: col=lane&15, row=(lane>>4)*4+reg  [verified layout]
__global__ __launch_bounds__(256)
void k_edge_mfma(const bf16* __restrict__ h, const void* __restrict__ ei,
                 const void* __restrict__ W1, const void* __restrict__ b1,
                 const void* __restrict__ W2, const void* __restrict__ b2,
                 void* __restrict__ outv, const int* __restrict__ flags)
{
  int xf32 = flags[0], ei64 = flags[1];
  int tid = threadIdx.x;
  int lane = tid & 63;
  int wv = tid >> 6;
  int r = lane & 15;        // A-row (edge) / B-col (outf) / D-col
  int g = lane >> 4;        // k sub-group

  // B fragments: Bf[kb][nb][e] = W1[kb*32 + 8g + e][nb*16 + r], once per block
  short8v Bf[4][4];
  #pragma unroll
  for (int kb = 0; kb < 4; ++kb)
    #pragma unroll
    for (int nb = 0; nb < 4; ++nb) {
      short8v v;
      #pragma unroll
      for (int e = 0; e < 8; ++e) {
        float w = load_f(W1, (long long)(kb * 32 + 8 * g + e) * 64 + nb * 16 + r, xf32);
        bf16 hb = __float2bfloat16(w);
        v[e] = *reinterpret_cast<short*>(&hb);
      }
      Bf[kb][nb] = v;
    }
  float b1v[4], w2v[4];
  #pragma unroll
  for (int nb = 0; nb < 4; ++nb) {
    b1v[nb] = load_f(b1, nb * 16 + r, xf32);
    w2v[nb] = load_f(W2, nb * 16 + r, xf32);
  }
  float b2v = load_f(b2, 0, xf32);

  const int NT = NE / 16;
  int nw = gridDim.x * 4;
  for (int t = blockIdx.x * 4 + wv; t < NT; t += nw) {
    int e0 = t * 16;
    int s = load_idx(ei, e0 + r, ei64);
    int d = load_idx(ei, (long long)NE + e0 + r, ei64);
    const short8v* pS = reinterpret_cast<const short8v*>(h + (long long)s * OUTF + g * 8);
    const short8v* pD = reinterpret_cast<const short8v*>(h + (long long)d * OUTF + g * 8);
    short8v A0 = pS[0];          // he k in [0,32)
    short8v A1 = pS[4];          // he k in [32,64)   (+32 bf16 = +4 short8v)
    short8v A2 = pD[0];          // he k in [64,96)
    short8v A3 = pD[4];          // he k in [96,128)

    float4v acc[4];
    #pragma unroll
    for (int nb = 0; nb < 4; ++nb)
      acc[nb] = (float4v){b1v[nb], b1v[nb], b1v[nb], b1v[nb]};
    #pragma unroll
    for (int nb = 0; nb < 4; ++nb) {
      acc[nb] = __builtin_amdgcn_mfma_f32_16x16x32_bf16(A0, Bf[0][nb], acc[nb], 0, 0, 0);
      acc[nb] = __builtin_amdgcn_mfma_f32_16x16x32_bf16(A1, Bf[1][nb], acc[nb], 0, 0, 0);
      acc[nb] = __builtin_amdgcn_mfma_f32_16x16x32_bf16(A2, Bf[2][nb], acc[nb], 0, 0, 0);
      acc[nb] = __builtin_amdgcn_mfma_f32_16x16x32_bf16(A3, Bf[3][nb], acc[nb], 0, 0, 0);
    }

    // layer 2: z[e] = sum_c tanh(acc[e][c]) * W2[c]; reduce over 16-lane col group
    float p[4];
    #pragma unroll
    for (int j = 0; j < 4; ++j) {
      float z = 0.0f;
      #pragma unroll
      for (int nb = 0; nb < 4; ++nb) z += fast_tanh(acc[nb][j]) * w2v[nb];
      z += __shfl_xor(z, 1, 64);
      z += __shfl_xor(z, 2, 64);
      z += __shfl_xor(z, 4, 64);
      z += __shfl_xor(z, 8, 64);
      p[j] = z;
    }
    if (r < 4) {
      float z = p[0];
      z = (r == 1) ? p[1] : z;
      z = (r == 2) ? p[2] : z;
      z = (r == 3) ? p[3] : z;
      float y = fast_tanh(z + b2v);
      float res = __builtin_amdgcn_rcpf(1.0f + __expf(-y));
      long long eo = (long long)e0 + g * 4 + r;
      if (xf32) ((float*)outv)[eo] = res;
      else      ((bf16*)outv)[eo] = __float2bfloat16(res);
    }
  }
}

extern "C" void kernel_launch(void* const* d_in, const int* in_sizes, int n_in,
                              void* d_out, int out_size, void* d_ws, size_t ws_size,
                              hipStream_t stream)
{
  const void* x  = d_in[0];
  const void* ei = d_in[1];
  const void* Wl = d_in[2];
  const void* Wr = d_in[3];
  const void* bl = d_in[4];
  const void* W1 = d_in[5];
  const void* b1 = d_in[6];
  const void* W2 = d_in[7];
  const void* b2 = d_in[8];

  char* ws = (char*)d_ws;
  float* agg = (float*)ws;                                  // NN*32 f32 = 12.8 MB (later aliased as bf16 h)
  float* cnt = (float*)(ws + (size_t)NN * INF * 4);         // NN f32 = 0.4 MB
  int* flags = (int*)(ws + (size_t)NN * INF * 4 + (size_t)NN * 4);

  k_detect<<<1, 64, 0, stream>>>(x, ei, flags);
  hipMemsetAsync(agg, 0, (size_t)NN * INF * 4 + (size_t)NN * 4, stream);

  k_agg<<<(NE * 32) / 256, 256, 0, stream>>>(x, ei, agg, cnt, flags);
  k_node<<<NN / 4, 256, 0, stream>>>(x, agg, cnt, Wl, Wr, bl, flags);
  k_edge_mfma<<<2048, 256, 0, stream>>>((const bf16*)agg, ei, W1, b1, W2, b2, d_out, flags);
}

// Round 4
// 429.277 us; speedup vs baseline: 4.1729x; 1.3812x over previous
//
#include <hip/hip_runtime.h>
#include <hip/hip_bf16.h>

#define NN 100000
#define NE 1600000
#define INF 32
#define OUTF 64

typedef __hip_bfloat16 bf16;
typedef unsigned long long u64;
typedef __attribute__((ext_vector_type(8))) short short8v;
typedef __attribute__((ext_vector_type(4))) float float4v;

__device__ __forceinline__ float load_f(const void* p, long long i, int f32) {
  return f32 ? ((const float*)p)[i] : __bfloat162float(((const bf16*)p)[i]);
}
__device__ __forceinline__ int load_idx(const void* p, long long i, int i64) {
  return i64 ? (int)((const long long*)p)[i] : ((const int*)p)[i];
}
__device__ __forceinline__ float fast_tanh(float x) {
  float e = __expf(2.0f * x);
  return 1.0f - 2.0f * __builtin_amdgcn_rcpf(e + 1.0f);
}
__device__ __forceinline__ bf16 f2b(float f) { return __float2bfloat16(f); }
__device__ __forceinline__ short bf_bits(float f) {
  bf16 h = __float2bfloat16(f);
  return *reinterpret_cast<short*>(&h);
}
__device__ __forceinline__ unsigned enc_fx(float v) {
  v = fminf(fmaxf(v, -7.99f), 7.99f);
  return (unsigned)rintf((v + 8.0f) * 64.0f);
}

// ---- kernel 0: dtype detector (1 block, 64 threads) ----
__global__ void k_detect(const void* __restrict__ x, const void* __restrict__ ei,
                         int* __restrict__ flags)
{
  int t = threadIdx.x;
  const unsigned* xu = (const unsigned*)x;
  int hits = 0;
  #pragma unroll
  for (int i = 0; i < 16; ++i) {
    unsigned w = xu[t * 16 + i];
    unsigned mid = (w >> 7) & 0xFF;
    hits += (mid >= 0x70 && mid <= 0x86) ? 1 : 0;
  }
  #pragma unroll
  for (int off = 32; off > 0; off >>= 1) hits += __shfl_xor(hits, off, 64);
  const int* e32 = (const int*)ei;
  unsigned long long m = __ballot(e32[2 * t + 1] == 0);
  if (t == 0) {
    flags[0] = (hits < 512) ? 1 : 0;   // 1 => floats are f32
    flags[1] = (m == ~0ULL) ? 1 : 0;   // 1 => edge_index is int64
  }
}

// ---- kernel 1: scatter-aggregate, 4 features packed per u64 fixed-point atomic ----
// field j of pa[dst*8+q] accumulates rint((x[src][4q+j]+8)*64); decode: field/64 - 8*cnt
__global__ __launch_bounds__(256)
void k_agg(const void* __restrict__ x, const void* __restrict__ ei,
           u64* __restrict__ pa, int* __restrict__ icnt,
           const int* __restrict__ flags)
{
  int xf32 = flags[0], ei64 = flags[1];
  long long gid = (long long)blockIdx.x * 256 + threadIdx.x;
  int e = (int)(gid >> 3);
  int q = (int)(gid & 7);
  int src = load_idx(ei, e, ei64);
  int dst = load_idx(ei, (long long)NE + e, ei64);
  float v0, v1, v2, v3;
  if (xf32) {
    float4 v = ((const float4*)x)[(long long)src * 8 + q];
    v0 = v.x; v1 = v.y; v2 = v.z; v3 = v.w;
  } else {
    uint2 w = *(const uint2*)((const bf16*)x + (long long)src * 32 + q * 4);
    v0 = __uint_as_float(w.x << 16);
    v1 = __uint_as_float(w.x & 0xffff0000u);
    v2 = __uint_as_float(w.y << 16);
    v3 = __uint_as_float(w.y & 0xffff0000u);
  }
  u64 pk = (u64)enc_fx(v0) | ((u64)enc_fx(v1) << 16)
         | ((u64)enc_fx(v2) << 32) | ((u64)enc_fx(v3) << 48);
  atomicAdd(&pa[(long long)dst * 8 + q], pk);
  if (q == 0) atomicAdd(&icnt[dst], 1);
}

// ---- kernel 2: h = tanh([mean|x] @ [Wl;Wr] + b_l) via MFMA, 16 nodes per wave-tile ----
// A row=lane&15 (node), k=8*(lane>>4)+e ; D: col=lane&15, row=(lane>>4)*4+reg
__global__ __launch_bounds__(256)
void k_node_mfma(const void* __restrict__ x, const u64* __restrict__ pa,
                 const int* __restrict__ icnt,
                 const void* __restrict__ Wl, const void* __restrict__ Wr,
                 const void* __restrict__ bl, bf16* __restrict__ h,
                 const int* __restrict__ flags)
{
  int xf32 = flags[0];
  int lane = threadIdx.x & 63;
  int wv = threadIdx.x >> 6;
  int r = lane & 15;
  int g = lane >> 4;

  short8v Bf[2][4];                 // kb=0: Wl rows (k=8g+e), kb=1: Wr rows
  #pragma unroll
  for (int kb = 0; kb < 2; ++kb) {
    const void* W = kb ? Wr : Wl;
    #pragma unroll
    for (int nb = 0; nb < 4; ++nb) {
      short8v v;
      #pragma unroll
      for (int e = 0; e < 8; ++e)
        v[e] = bf_bits(load_f(W, (long long)(8 * g + e) * 64 + nb * 16 + r, xf32));
      Bf[kb][nb] = v;
    }
  }
  float blv[4];
  #pragma unroll
  for (int nb = 0; nb < 4; ++nb) blv[nb] = load_f(bl, nb * 16 + r, xf32);

  const int NT = NN / 16;           // 6250
  int nw = gridDim.x * 4;
  for (int t = blockIdx.x * 4 + wv; t < NT; t += nw) {
    int n0 = t * 16;
    int node = n0 + r;
    int cnt = icnt[node];
    float s = (cnt > 0) ? __builtin_amdgcn_rcpf(64.0f * cnt) : 0.0f;
    float bias = (cnt > 0) ? 8.0f : 0.0f;
    u64 p0 = pa[(long long)node * 8 + 2 * g];
    u64 p1 = pa[(long long)node * 8 + 2 * g + 1];
    short8v A0, A1;
    #pragma unroll
    for (int j = 0; j < 4; ++j) {
      A0[j]     = bf_bits((float)((p0 >> (16 * j)) & 0xffff) * s - bias);
      A0[4 + j] = bf_bits((float)((p1 >> (16 * j)) & 0xffff) * s - bias);
    }
    if (xf32) {
      const float* xp = (const float*)x + (long long)node * 32 + 8 * g;
      #pragma unroll
      for (int e = 0; e < 8; ++e) A1[e] = bf_bits(xp[e]);
    } else {
      A1 = *(const short8v*)((const bf16*)x + (long long)node * 32 + 8 * g);
    }

    float4v acc[4];
    #pragma unroll
    for (int nb = 0; nb < 4; ++nb) {
      acc[nb] = (float4v){blv[nb], blv[nb], blv[nb], blv[nb]};
      acc[nb] = __builtin_amdgcn_mfma_f32_16x16x32_bf16(A0, Bf[0][nb], acc[nb], 0, 0, 0);
      acc[nb] = __builtin_amdgcn_mfma_f32_16x16x32_bf16(A1, Bf[1][nb], acc[nb], 0, 0, 0);
    }
    #pragma unroll
    for (int nb = 0; nb < 4; ++nb)
      #pragma unroll
      for (int j = 0; j < 4; ++j) {
        int nd = n0 + 4 * g + j;
        h[(long long)nd * OUTF + nb * 16 + r] = f2b(fast_tanh(acc[nb][j]));
      }
  }
}

// ---- kernel 3: per-edge MLP via MFMA (validated R3) ----
__global__ __launch_bounds__(256)
void k_edge_mfma(const bf16* __restrict__ h, const void* __restrict__ ei,
                 const void* __restrict__ W1, const void* __restrict__ b1,
                 const void* __restrict__ W2, const void* __restrict__ b2,
                 void* __restrict__ outv, const int* __restrict__ flags)
{
  int xf32 = flags[0], ei64 = flags[1];
  int lane = threadIdx.x & 63;
  int wv = threadIdx.x >> 6;
  int r = lane & 15;
  int g = lane >> 4;

  short8v Bf[4][4];
  #pragma unroll
  for (int kb = 0; kb < 4; ++kb)
    #pragma unroll
    for (int nb = 0; nb < 4; ++nb) {
      short8v v;
      #pragma unroll
      for (int e = 0; e < 8; ++e)
        v[e] = bf_bits(load_f(W1, (long long)(kb * 32 + 8 * g + e) * 64 + nb * 16 + r, xf32));
      Bf[kb][nb] = v;
    }
  float b1v[4], w2v[4];
  #pragma unroll
  for (int nb = 0; nb < 4; ++nb) {
    b1v[nb] = load_f(b1, nb * 16 + r, xf32);
    w2v[nb] = load_f(W2, nb * 16 + r, xf32);
  }
  float b2v = load_f(b2, 0, xf32);

  const int NT = NE / 16;
  int nw = gridDim.x * 4;
  for (int t = blockIdx.x * 4 + wv; t < NT; t += nw) {
    int e0 = t * 16;
    int s = load_idx(ei, e0 + r, ei64);
    int d = load_idx(ei, (long long)NE + e0 + r, ei64);
    const short8v* pS = reinterpret_cast<const short8v*>(h + (long long)s * OUTF + g * 8);
    const short8v* pD = reinterpret_cast<const short8v*>(h + (long long)d * OUTF + g * 8);
    short8v A0 = pS[0];
    short8v A1 = pS[4];
    short8v A2 = pD[0];
    short8v A3 = pD[4];

    float4v acc[4];
    #pragma unroll
    for (int nb = 0; nb < 4; ++nb)
      acc[nb] = (float4v){b1v[nb], b1v[nb], b1v[nb], b1v[nb]};
    #pragma unroll
    for (int nb = 0; nb < 4; ++nb) {
      acc[nb] = __builtin_amdgcn_mfma_f32_16x16x32_bf16(A0, Bf[0][nb], acc[nb], 0, 0, 0);
      acc[nb] = __builtin_amdgcn_mfma_f32_16x16x32_bf16(A1, Bf[1][nb], acc[nb], 0, 0, 0);
      acc[nb] = __builtin_amdgcn_mfma_f32_16x16x32_bf16(A2, Bf[2][nb], acc[nb], 0, 0, 0);
      acc[nb] = __builtin_amdgcn_mfma_f32_16x16x32_bf16(A3, Bf[3][nb], acc[nb], 0, 0, 0);
    }

    float p[4];
    #pragma unroll
    for (int j = 0; j < 4; ++j) {
      float z = 0.0f;
      #pragma unroll
      for (int nb = 0; nb < 4; ++nb) z += fast_tanh(acc[nb][j]) * w2v[nb];
      z += __shfl_xor(z, 1, 64);
      z += __shfl_xor(z, 2, 64);
      z += __shfl_xor(z, 4, 64);
      z += __shfl_xor(z, 8, 64);
      p[j] = z;
    }
    if (r < 4) {
      float z = p[0];
      z = (r == 1) ? p[1] : z;
      z = (r == 2) ? p[2] : z;
      z = (r == 3) ? p[3] : z;
      float y = fast_tanh(z + b2v);
      float res = __builtin_amdgcn_rcpf(1.0f + __expf(-y));
      long long eo = (long long)e0 + g * 4 + r;
      if (xf32) ((float*)outv)[eo] = res;
      else      ((bf16*)outv)[eo] = f2b(res);
    }
  }
}

extern "C" void kernel_launch(void* const* d_in, const int* in_sizes, int n_in,
                              void* d_out, int out_size, void* d_ws, size_t ws_size,
                              hipStream_t stream)
{
  const void* x  = d_in[0];
  const void* ei = d_in[1];
  const void* Wl = d_in[2];
  const void* Wr = d_in[3];
  const void* bl = d_in[4];
  const void* W1 = d_in[5];
  const void* b1 = d_in[6];
  const void* W2 = d_in[7];
  const void* b2 = d_in[8];

  char* ws = (char*)d_ws;
  u64*  pa    = (u64*)ws;                                   // NN*8 u64  = 6.4 MB
  int*  icnt  = (int*)(ws + (size_t)NN * 64);               // NN int    = 0.4 MB
  int*  flags = (int*)(ws + (size_t)NN * 64 + (size_t)NN * 4);
  bf16* h     = (bf16*)(ws + (size_t)8 * 1024 * 1024);      // NN*64 bf16 = 12.8 MB

  k_detect<<<1, 64, 0, stream>>>(x, ei, flags);
  hipMemsetAsync(pa, 0, (size_t)NN * 64 + (size_t)NN * 4, stream);

  k_agg<<<(NE * 8) / 256, 256, 0, stream>>>(x, ei, pa, icnt, flags);
  k_node_mfma<<<512, 256, 0, stream>>>(x, pa, icnt, Wl, Wr, bl, h, flags);
  k_edge_mfma<<<2048, 256, 0, stream>>>(h, ei, W1, b1, W2, b2, d_out, flags);
}

// Round 7
// 321.627 us; speedup vs baseline: 5.5696x; 1.3347x over previous
//
#include <hip/hip_runtime.h>
#include <hip/hip_bf16.h>

#define NN 100000
#define NE 1600000
#define INF 32
#define OUTF 64

typedef __hip_bfloat16 bf16;
typedef unsigned long long u64;
typedef __attribute__((ext_vector_type(8))) short short8v;
typedef __attribute__((ext_vector_type(4))) float float4v;

__device__ __forceinline__ float load_f(const void* p, long long i, int f32) {
  return f32 ? ((const float*)p)[i] : __bfloat162float(((const bf16*)p)[i]);
}
__device__ __forceinline__ int load_idx(const void* p, long long i, int i64) {
  return i64 ? (int)((const long long*)p)[i] : ((const int*)p)[i];
}
__device__ __forceinline__ float fast_tanh(float x) {
  float e = __expf(2.0f * x);
  return 1.0f - 2.0f * __builtin_amdgcn_rcpf(e + 1.0f);
}
__device__ __forceinline__ bf16 f2b(float f) { return __float2bfloat16(f); }
__device__ __forceinline__ short bf_bits(float f) {
  bf16 h = __float2bfloat16(f);
  return *reinterpret_cast<short*>(&h);
}
__device__ __forceinline__ float s2f(short s) {        // bf16 bits -> f32
  return __uint_as_float(((unsigned)(unsigned short)s) << 16);
}
__device__ __forceinline__ unsigned enc_fx(float v) {
  v = fminf(fmaxf(v, -7.99f), 7.99f);
  return (unsigned)rintf((v + 8.0f) * 64.0f);
}

// ---- kernel 0: dtype detector ----
__global__ void k_detect(const void* __restrict__ x, const void* __restrict__ ei,
                         int* __restrict__ flags)
{
  int t = threadIdx.x;
  const unsigned* xu = (const unsigned*)x;
  int hits = 0;
  #pragma unroll
  for (int i = 0; i < 16; ++i) {
    unsigned w = xu[t * 16 + i];
    unsigned mid = (w >> 7) & 0xFF;
    hits += (mid >= 0x70 && mid <= 0x86) ? 1 : 0;
  }
  #pragma unroll
  for (int off = 32; off > 0; off >>= 1) hits += __shfl_xor(hits, off, 64);
  const int* e32 = (const int*)ei;
  unsigned long long m = __ballot(e32[2 * t + 1] == 0);
  if (t == 0) {
    flags[0] = (hits < 512) ? 1 : 0;   // 1 => floats are f32
    flags[1] = (m == ~0ULL) ? 1 : 0;   // 1 => edge_index is int64
  }
}

// ---- kernel 1: scatter-aggregate, packed u64 fixed-point atomics; idx deduped via shfl ----
__global__ __launch_bounds__(256)
void k_agg(const void* __restrict__ x, const void* __restrict__ ei,
           u64* __restrict__ pa, int* __restrict__ icnt,
           const int* __restrict__ flags)
{
  int xf32 = flags[0], ei64 = flags[1];
  long long gid = (long long)blockIdx.x * 256 + threadIdx.x;
  int e = (int)(gid >> 3);
  int lane = threadIdx.x & 63;
  int q = lane & 7;
  // 8-lane group shares edge e: lane q==0 loads src, q==1 loads dst, broadcast
  int iv = 0;
  if (q < 2) iv = load_idx(ei, (q ? (long long)NE : 0) + e, ei64);
  int base = lane & ~7;
  int src = __shfl(iv, base, 64);
  int dst = __shfl(iv, base | 1, 64);
  float v0, v1, v2, v3;
  if (xf32) {
    float4 v = ((const float4*)x)[(long long)src * 8 + q];
    v0 = v.x; v1 = v.y; v2 = v.z; v3 = v.w;
  } else {
    uint2 w = *(const uint2*)((const bf16*)x + (long long)src * 32 + q * 4);
    v0 = __uint_as_float(w.x << 16);
    v1 = __uint_as_float(w.x & 0xffff0000u);
    v2 = __uint_as_float(w.y << 16);
    v3 = __uint_as_float(w.y & 0xffff0000u);
  }
  u64 pk = (u64)enc_fx(v0) | ((u64)enc_fx(v1) << 16)
         | ((u64)enc_fx(v2) << 32) | ((u64)enc_fx(v3) << 48);
  atomicAdd(&pa[(long long)dst * 8 + q], pk);
  if (q == 0) atomicAdd(&icnt[dst], 1);
}

// ---- kernel 2: fused node stage ----
// h = tanh([mean|x] @ [Wl;Wr] + bl)  (registers -> LDS transpose, never global)
// U = h @ W1[0:64]  + b1   (bf16 out)
// V = h @ W1[64:128]       (bf16 out)
__global__ __launch_bounds__(256)
void k_node_uv(const void* __restrict__ x, const u64* __restrict__ pa,
               const int* __restrict__ icnt,
               const void* __restrict__ Wl, const void* __restrict__ Wr,
               const void* __restrict__ bl,
               const void* __restrict__ W1, const void* __restrict__ b1,
               bf16* __restrict__ U, bf16* __restrict__ V,
               const int* __restrict__ flags)
{
  __shared__ bf16 sh[4][16][64];     // per-wave h tile, [node][feat]
  int xf32 = flags[0];
  int lane = threadIdx.x & 63, wv = threadIdx.x >> 6;
  int r = lane & 15, g = lane >> 4;

  short8v Bh[2][4];                  // Wl (kb=0), Wr (kb=1)
  #pragma unroll
  for (int kb = 0; kb < 2; ++kb) {
    const void* W = kb ? Wr : Wl;
    #pragma unroll
    for (int nb = 0; nb < 4; ++nb) {
      short8v v;
      #pragma unroll
      for (int e = 0; e < 8; ++e)
        v[e] = bf_bits(load_f(W, (long long)(8 * g + e) * 64 + nb * 16 + r, xf32));
      Bh[kb][nb] = v;
    }
  }
  short8v Bf[4][4];                  // W1 rows kb*32+8g+e
  #pragma unroll
  for (int kb = 0; kb < 4; ++kb)
    #pragma unroll
    for (int nb = 0; nb < 4; ++nb) {
      short8v v;
      #pragma unroll
      for (int e = 0; e < 8; ++e)
        v[e] = bf_bits(load_f(W1, (long long)(kb * 32 + 8 * g + e) * 64 + nb * 16 + r, xf32));
      Bf[kb][nb] = v;
    }
  float blv[4], b1v[4];
  #pragma unroll
  for (int nb = 0; nb < 4; ++nb) {
    blv[nb] = load_f(bl, nb * 16 + r, xf32);
    b1v[nb] = load_f(b1, nb * 16 + r, xf32);
  }

  const int NT2 = NN / 16;           // 6250
  int nw = gridDim.x * 4;
  for (int t = blockIdx.x * 4 + wv; t < NT2; t += nw) {
    int n0 = t * 16;
    int node = n0 + r;
    int cnt = icnt[node];
    float s = (cnt > 0) ? __builtin_amdgcn_rcpf(64.0f * cnt) : 0.0f;
    float bias = (cnt > 0) ? 8.0f : 0.0f;
    u64 p0 = pa[(long long)node * 8 + 2 * g];
    u64 p1 = pa[(long long)node * 8 + 2 * g + 1];
    short8v A0, A1;
    #pragma unroll
    for (int j = 0; j < 4; ++j) {
      A0[j]     = bf_bits((float)((p0 >> (16 * j)) & 0xffff) * s - bias);
      A0[4 + j] = bf_bits((float)((p1 >> (16 * j)) & 0xffff) * s - bias);
    }
    if (xf32) {
      const float* xp = (const float*)x + (long long)node * 32 + 8 * g;
      #pragma unroll
      for (int e = 0; e < 8; ++e) A1[e] = bf_bits(xp[e]);
    } else {
      A1 = *(const short8v*)((const bf16*)x + (long long)node * 32 + 8 * g);
    }

    // h stage -> LDS (A-layout transpose)
    #pragma unroll
    for (int nb = 0; nb < 4; ++nb) {
      float4v acc = (float4v){blv[nb], blv[nb], blv[nb], blv[nb]};
      acc = __builtin_amdgcn_mfma_f32_16x16x32_bf16(A0, Bh[0][nb], acc, 0, 0, 0);
      acc = __builtin_amdgcn_mfma_f32_16x16x32_bf16(A1, Bh[1][nb], acc, 0, 0, 0);
      #pragma unroll
      for (int j = 0; j < 4; ++j)
        sh[wv][4 * g + j][nb * 16 + r] = f2b(fast_tanh(acc[j]));
    }
    asm volatile("s_waitcnt lgkmcnt(0)" ::: "memory");
    __builtin_amdgcn_sched_barrier(0);
    short8v Ah0 = *(const short8v*)&sh[wv][r][8 * g];
    short8v Ah1 = *(const short8v*)&sh[wv][r][32 + 8 * g];

    #pragma unroll
    for (int nb = 0; nb < 4; ++nb) {
      float4v au = (float4v){b1v[nb], b1v[nb], b1v[nb], b1v[nb]};
      au = __builtin_amdgcn_mfma_f32_16x16x32_bf16(Ah0, Bf[0][nb], au, 0, 0, 0);
      au = __builtin_amdgcn_mfma_f32_16x16x32_bf16(Ah1, Bf[1][nb], au, 0, 0, 0);
      float4v av = (float4v){0.0f, 0.0f, 0.0f, 0.0f};
      av = __builtin_amdgcn_mfma_f32_16x16x32_bf16(Ah0, Bf[2][nb], av, 0, 0, 0);
      av = __builtin_amdgcn_mfma_f32_16x16x32_bf16(Ah1, Bf[3][nb], av, 0, 0, 0);
      #pragma unroll
      for (int j = 0; j < 4; ++j) {
        long long row = (long long)(n0 + 4 * g + j) * 64 + nb * 16 + r;
        U[row] = f2b(au[j]);
        V[row] = f2b(av[j]);
      }
    }
    asm volatile("s_waitcnt lgkmcnt(0)" ::: "memory");
    __builtin_amdgcn_sched_barrier(0);
  }
}

// ---- kernel 3: per-edge: out = sigmoid(tanh( sum_c tanh(U[s][c]+V[d][c]) * W2[c] + b2 )) ----
// wave = 16 edges/iter, 4 lanes per edge (lane j covers cols 16j..16j+15)
// 3-stage pipeline: idx(t+2) | UV(t+1) | compute(t)
struct UVfrag { short8v u0, u1, v0, v1; };

__device__ __forceinline__ int ld_idx16(const void* ei, long long t, int NT,
                                        int lane, int ei64)
{
  long long tt = (t < NT) ? t : (NT - 1);
  long long e0 = tt * 16;
  int iv = 0;
  if (lane < 32) {
    long long off = (lane < 16) ? (e0 + lane) : ((long long)NE + e0 + (lane - 16));
    iv = ei64 ? (int)((const long long*)ei)[off] : ((const int*)ei)[off];
  }
  return iv;
}
__device__ __forceinline__ UVfrag ld_uv(const bf16* U, const bf16* V,
                                        int iv, int e4, int j)
{
  int sB = __shfl(iv, e4, 64);
  int dB = __shfl(iv, 16 + e4, 64);
  UVfrag f;
  const short8v* pu = (const short8v*)(U + (long long)sB * 64) + j * 2;
  f.u0 = pu[0]; f.u1 = pu[1];
  const short8v* pv = (const short8v*)(V + (long long)dB * 64) + j * 2;
  f.v0 = pv[0]; f.v1 = pv[1];
  return f;
}

__global__ __launch_bounds__(256)
void k_edge2(const bf16* __restrict__ U, const bf16* __restrict__ V,
             const void* __restrict__ ei,
             const void* __restrict__ W2, const void* __restrict__ b2,
             void* __restrict__ outv, const int* __restrict__ flags)
{
  int xf32 = flags[0], ei64 = flags[1];
  int lane = threadIdx.x & 63, wv = threadIdx.x >> 6;
  int e4 = lane >> 2, j = lane & 3;
  float w2v[16];
  #pragma unroll
  for (int i = 0; i < 16; ++i) w2v[i] = load_f(W2, 16 * j + i, xf32);
  float b2v = load_f(b2, 0, xf32);

  const int NT = NE / 16;            // 100000
  int nw = gridDim.x * 4;
  long long w0 = blockIdx.x * 4 + wv;

  int ia = ld_idx16(ei, w0, NT, lane, ei64);
  UVfrag uvA = ld_uv(U, V, ia, e4, j);
  int ib = ld_idx16(ei, w0 + nw, NT, lane, ei64);

  for (long long t = w0; t < NT; t += nw) {
    int ic = ld_idx16(ei, t + 2 * (long long)nw, NT, lane, ei64);
    UVfrag uvB = ld_uv(U, V, ib, e4, j);

    float z = 0.0f;
    #pragma unroll
    for (int i = 0; i < 8; ++i)
      z += fast_tanh(s2f(uvA.u0[i]) + s2f(uvA.v0[i])) * w2v[i];
    #pragma unroll
    for (int i = 0; i < 8; ++i)
      z += fast_tanh(s2f(uvA.u1[i]) + s2f(uvA.v1[i])) * w2v[8 + i];
    z += __shfl_xor(z, 1, 64);
    z += __shfl_xor(z, 2, 64);
    if (j == 0) {
      float y = fast_tanh(z + b2v);
      float res = __builtin_amdgcn_rcpf(1.0f + __expf(-y));
      long long eo = t * 16 + e4;
      if (xf32) ((float*)outv)[eo] = res;
      else      ((bf16*)outv)[eo] = f2b(res);
    }
    ib = ic;
    uvA = uvB;
  }
}

extern "C" void kernel_launch(void* const* d_in, const int* in_sizes, int n_in,
                              void* d_out, int out_size, void* d_ws, size_t ws_size,
                              hipStream_t stream)
{
  const void* x  = d_in[0];
  const void* ei = d_in[1];
  const void* Wl = d_in[2];
  const void* Wr = d_in[3];
  const void* bl = d_in[4];
  const void* W1 = d_in[5];
  const void* b1 = d_in[6];
  const void* W2 = d_in[7];
  const void* b2 = d_in[8];

  char* ws = (char*)d_ws;
  // layout (bytes): pa[0, 6.4M) icnt[6.4M, 6.8M) U[6800384, +12.8M) V[19600384, +12.8M) flags[32400384)
  u64*  pa    = (u64*)ws;
  int*  icnt  = (int*)(ws + 6400000);
  bf16* U     = (bf16*)(ws + 6800384);
  bf16* V     = (bf16*)(ws + 19600384);
  int*  flags = (int*)(ws + 32400384);

  k_detect<<<1, 64, 0, stream>>>(x, ei, flags);
  hipMemsetAsync(pa, 0, 6800000, stream);

  k_agg<<<(NE * 8) / 256, 256, 0, stream>>>(x, ei, pa, icnt, flags);
  k_node_uv<<<512, 256, 0, stream>>>(x, pa, icnt, Wl, Wr, bl, W1, b1, U, V, flags);
  k_edge2<<<2048, 256, 0, stream>>>(U, V, ei, W2, b2, d_out, flags);
}

// Round 8
// 316.843 us; speedup vs baseline: 5.6537x; 1.0151x over previous
//
#include <hip/hip_runtime.h>
#include <hip/hip_bf16.h>

#define NN 100000
#define NE 1600000
#define INF 32
#define OUTF 64

typedef __hip_bfloat16 bf16;
typedef unsigned long long u64;
typedef __attribute__((ext_vector_type(8))) short short8v;
typedef __attribute__((ext_vector_type(4))) float float4v;
typedef __attribute__((ext_vector_type(2))) float floatx2;

__device__ __forceinline__ float load_f(const void* p, long long i, int f32) {
  return f32 ? ((const float*)p)[i] : __bfloat162float(((const bf16*)p)[i]);
}
__device__ __forceinline__ int load_idx(const void* p, long long i, int i64) {
  return i64 ? (int)((const long long*)p)[i] : ((const int*)p)[i];
}
__device__ __forceinline__ float fast_tanh(float x) {
  float e = __expf(2.0f * x);
  return 1.0f - 2.0f * __builtin_amdgcn_rcpf(e + 1.0f);
}
__device__ __forceinline__ bf16 f2b(float f) { return __float2bfloat16(f); }
__device__ __forceinline__ short bf_bits(float f) {
  bf16 h = __float2bfloat16(f);
  return *reinterpret_cast<short*>(&h);
}
__device__ __forceinline__ unsigned enc_fx(float v) {
  v = fminf(fmaxf(v, -7.99f), 7.99f);
  return (unsigned)rintf((v + 8.0f) * 64.0f);
}
__device__ __forceinline__ unsigned char f2fp8(float f) {
  unsigned p = __builtin_amdgcn_cvt_pk_fp8_f32(f, f, 0, false);
  return (unsigned char)(p & 0xFF);
}

// ---- kernel 0: dtype detector ----
__global__ void k_detect(const void* __restrict__ x, const void* __restrict__ ei,
                         int* __restrict__ flags)
{
  int t = threadIdx.x;
  const unsigned* xu = (const unsigned*)x;
  int hits = 0;
  #pragma unroll
  for (int i = 0; i < 16; ++i) {
    unsigned w = xu[t * 16 + i];
    unsigned mid = (w >> 7) & 0xFF;
    hits += (mid >= 0x70 && mid <= 0x86) ? 1 : 0;
  }
  #pragma unroll
  for (int off = 32; off > 0; off >>= 1) hits += __shfl_xor(hits, off, 64);
  const int* e32 = (const int*)ei;
  unsigned long long m = __ballot(e32[2 * t + 1] == 0);
  if (t == 0) {
    flags[0] = (hits < 512) ? 1 : 0;   // 1 => floats are f32
    flags[1] = (m == ~0ULL) ? 1 : 0;   // 1 => edge_index is int64
  }
}

// ---- kernel 1a: pre-encode x rows into packed u64 fixed-point (once per node) ----
__global__ __launch_bounds__(256)
void k_prep(const void* __restrict__ x, u64* __restrict__ penc,
            const int* __restrict__ flags)
{
  int xf32 = flags[0];
  int i = blockIdx.x * 256 + threadIdx.x;      // i = node*8 + q, i < 800000
  float v0, v1, v2, v3;
  if (xf32) {
    float4 v = ((const float4*)x)[i];
    v0 = v.x; v1 = v.y; v2 = v.z; v3 = v.w;
  } else {
    uint2 w = ((const uint2*)x)[i];
    v0 = __uint_as_float(w.x << 16);
    v1 = __uint_as_float(w.x & 0xffff0000u);
    v2 = __uint_as_float(w.y << 16);
    v3 = __uint_as_float(w.y & 0xffff0000u);
  }
  penc[i] = (u64)enc_fx(v0) | ((u64)enc_fx(v1) << 16)
          | ((u64)enc_fx(v2) << 32) | ((u64)enc_fx(v3) << 48);
}

// ---- kernel 1b: scatter-aggregate: gather 64B penc row, atomicAdd u64 ----
__global__ __launch_bounds__(256)
void k_agg(const u64* __restrict__ penc, const void* __restrict__ ei,
           u64* __restrict__ pa, int* __restrict__ icnt,
           const int* __restrict__ flags)
{
  int ei64 = flags[1];
  long long gid = (long long)blockIdx.x * 256 + threadIdx.x;
  int e = (int)(gid >> 3);
  int lane = threadIdx.x & 63;
  int q = lane & 7;
  int iv = 0;
  if (q < 2) iv = load_idx(ei, (q ? (long long)NE : 0) + e, ei64);
  int base = lane & ~7;
  int src = __shfl(iv, base, 64);
  int dst = __shfl(iv, base | 1, 64);
  u64 pk = penc[(long long)src * 8 + q];
  atomicAdd(&pa[(long long)dst * 8 + q], pk);
  if (q == 0) atomicAdd(&icnt[dst], 1);
}

// ---- kernel 2: fused node stage ----
// h = tanh([mean|x] @ [Wl;Wr] + bl)  (registers -> LDS transpose, never global)
// U8 = fp8(h @ W1[0:64] + b1), V8 = fp8(h @ W1[64:128])
__global__ __launch_bounds__(256)
void k_node_uv(const void* __restrict__ x, const u64* __restrict__ pa,
               const int* __restrict__ icnt,
               const void* __restrict__ Wl, const void* __restrict__ Wr,
               const void* __restrict__ bl,
               const void* __restrict__ W1, const void* __restrict__ b1,
               unsigned char* __restrict__ U8, unsigned char* __restrict__ V8,
               const int* __restrict__ flags)
{
  __shared__ bf16 sh[4][16][64];     // per-wave h tile, [node][feat]
  int xf32 = flags[0];
  int lane = threadIdx.x & 63, wv = threadIdx.x >> 6;
  int r = lane & 15, g = lane >> 4;

  short8v Bh[2][4];                  // Wl (kb=0), Wr (kb=1)
  #pragma unroll
  for (int kb = 0; kb < 2; ++kb) {
    const void* W = kb ? Wr : Wl;
    #pragma unroll
    for (int nb = 0; nb < 4; ++nb) {
      short8v v;
      #pragma unroll
      for (int e = 0; e < 8; ++e)
        v[e] = bf_bits(load_f(W, (long long)(8 * g + e) * 64 + nb * 16 + r, xf32));
      Bh[kb][nb] = v;
    }
  }
  short8v Bf[4][4];                  // W1 rows kb*32+8g+e
  #pragma unroll
  for (int kb = 0; kb < 4; ++kb)
    #pragma unroll
    for (int nb = 0; nb < 4; ++nb) {
      short8v v;
      #pragma unroll
      for (int e = 0; e < 8; ++e)
        v[e] = bf_bits(load_f(W1, (long long)(kb * 32 + 8 * g + e) * 64 + nb * 16 + r, xf32));
      Bf[kb][nb] = v;
    }
  float blv[4], b1v[4];
  #pragma unroll
  for (int nb = 0; nb < 4; ++nb) {
    blv[nb] = load_f(bl, nb * 16 + r, xf32);
    b1v[nb] = load_f(b1, nb * 16 + r, xf32);
  }

  const int NT2 = NN / 16;           // 6250
  int nw = gridDim.x * 4;
  for (int t = blockIdx.x * 4 + wv; t < NT2; t += nw) {
    int n0 = t * 16;
    int node = n0 + r;
    int cnt = icnt[node];
    float s = (cnt > 0) ? __builtin_amdgcn_rcpf(64.0f * cnt) : 0.0f;
    float bias = (cnt > 0) ? 8.0f : 0.0f;
    u64 p0 = pa[(long long)node * 8 + 2 * g];
    u64 p1 = pa[(long long)node * 8 + 2 * g + 1];
    short8v A0, A1;
    #pragma unroll
    for (int j = 0; j < 4; ++j) {
      A0[j]     = bf_bits((float)((p0 >> (16 * j)) & 0xffff) * s - bias);
      A0[4 + j] = bf_bits((float)((p1 >> (16 * j)) & 0xffff) * s - bias);
    }
    if (xf32) {
      const float* xp = (const float*)x + (long long)node * 32 + 8 * g;
      #pragma unroll
      for (int e = 0; e < 8; ++e) A1[e] = bf_bits(xp[e]);
    } else {
      A1 = *(const short8v*)((const bf16*)x + (long long)node * 32 + 8 * g);
    }

    // h stage -> LDS (A-layout transpose)
    #pragma unroll
    for (int nb = 0; nb < 4; ++nb) {
      float4v acc = (float4v){blv[nb], blv[nb], blv[nb], blv[nb]};
      acc = __builtin_amdgcn_mfma_f32_16x16x32_bf16(A0, Bh[0][nb], acc, 0, 0, 0);
      acc = __builtin_amdgcn_mfma_f32_16x16x32_bf16(A1, Bh[1][nb], acc, 0, 0, 0);
      #pragma unroll
      for (int j = 0; j < 4; ++j)
        sh[wv][4 * g + j][nb * 16 + r] = f2b(fast_tanh(acc[j]));
    }
    asm volatile("s_waitcnt lgkmcnt(0)" ::: "memory");
    __builtin_amdgcn_sched_barrier(0);
    short8v Ah0 = *(const short8v*)&sh[wv][r][8 * g];
    short8v Ah1 = *(const short8v*)&sh[wv][r][32 + 8 * g];

    #pragma unroll
    for (int nb = 0; nb < 4; ++nb) {
      float4v au = (float4v){b1v[nb], b1v[nb], b1v[nb], b1v[nb]};
      au = __builtin_amdgcn_mfma_f32_16x16x32_bf16(Ah0, Bf[0][nb], au, 0, 0, 0);
      au = __builtin_amdgcn_mfma_f32_16x16x32_bf16(Ah1, Bf[1][nb], au, 0, 0, 0);
      float4v av = (float4v){0.0f, 0.0f, 0.0f, 0.0f};
      av = __builtin_amdgcn_mfma_f32_16x16x32_bf16(Ah0, Bf[2][nb], av, 0, 0, 0);
      av = __builtin_amdgcn_mfma_f32_16x16x32_bf16(Ah1, Bf[3][nb], av, 0, 0, 0);
      #pragma unroll
      for (int j = 0; j < 4; ++j) {
        long long row = (long long)(n0 + 4 * g + j) * 64 + nb * 16 + r;
        U8[row] = f2fp8(au[j]);
        V8[row] = f2fp8(av[j]);
      }
    }
    asm volatile("s_waitcnt lgkmcnt(0)" ::: "memory");
    __builtin_amdgcn_sched_barrier(0);
  }
}

// ---- kernel 3: per-edge: out = sigmoid(tanh( sum_c tanh(U[s][c]+V[d][c]) * W2[c] + b2 )) ----
// fp8 U/V rows (64B). wave = 16 edges/iter, 4 lanes/edge (lane j covers feats 16j..16j+15)
// 3-stage pipeline: idx(t+2) | UV(t+1) | compute(t)
struct UV8 { uint4 u, v; };

__device__ __forceinline__ int ld_idx16(const void* ei, long long t, int NT,
                                        int lane, int ei64)
{
  long long tt = (t < NT) ? t : (NT - 1);
  long long e0 = tt * 16;
  int iv = 0;
  if (lane < 32) {
    long long off = (lane < 16) ? (e0 + lane) : ((long long)NE + e0 + (lane - 16));
    iv = ei64 ? (int)((const long long*)ei)[off] : ((const int*)ei)[off];
  }
  return iv;
}
__device__ __forceinline__ UV8 ld_uv8(const unsigned char* U8, const unsigned char* V8,
                                      int iv, int e4, int j)
{
  int sB = __shfl(iv, e4, 64);
  int dB = __shfl(iv, 16 + e4, 64);
  UV8 f;
  f.u = *(const uint4*)(U8 + (long long)sB * 64 + j * 16);
  f.v = *(const uint4*)(V8 + (long long)dB * 64 + j * 16);
  return f;
}

__global__ __launch_bounds__(256)
void k_edge2(const unsigned char* __restrict__ U8, const unsigned char* __restrict__ V8,
             const void* __restrict__ ei,
             const void* __restrict__ W2, const void* __restrict__ b2,
             void* __restrict__ outv, const int* __restrict__ flags)
{
  int xf32 = flags[0], ei64 = flags[1];
  int lane = threadIdx.x & 63, wv = threadIdx.x >> 6;
  int e4 = lane >> 2, j = lane & 3;
  float w2v[16];
  #pragma unroll
  for (int i = 0; i < 16; ++i) w2v[i] = load_f(W2, 16 * j + i, xf32);
  float b2v = load_f(b2, 0, xf32);

  const int NT = NE / 16;            // 100000
  int nw = gridDim.x * 4;
  long long w0 = blockIdx.x * 4 + wv;

  int ia = ld_idx16(ei, w0, NT, lane, ei64);
  UV8 uvA = ld_uv8(U8, V8, ia, e4, j);
  int ib = ld_idx16(ei, w0 + nw, NT, lane, ei64);

  for (long long t = w0; t < NT; t += nw) {
    int ic = ld_idx16(ei, t + 2 * (long long)nw, NT, lane, ei64);
    UV8 uvB = ld_uv8(U8, V8, ib, e4, j);

    unsigned ua[4] = {uvA.u.x, uvA.u.y, uvA.u.z, uvA.u.w};
    unsigned va[4] = {uvA.v.x, uvA.v.y, uvA.v.z, uvA.v.w};
    float z = 0.0f;
    #pragma unroll
    for (int d = 0; d < 4; ++d) {
      floatx2 ul = __builtin_amdgcn_cvt_pk_f32_fp8(ua[d], false);
      floatx2 uh = __builtin_amdgcn_cvt_pk_f32_fp8(ua[d], true);
      floatx2 vl = __builtin_amdgcn_cvt_pk_f32_fp8(va[d], false);
      floatx2 vh = __builtin_amdgcn_cvt_pk_f32_fp8(va[d], true);
      z += fast_tanh(ul.x + vl.x) * w2v[4 * d + 0];
      z += fast_tanh(ul.y + vl.y) * w2v[4 * d + 1];
      z += fast_tanh(uh.x + vh.x) * w2v[4 * d + 2];
      z += fast_tanh(uh.y + vh.y) * w2v[4 * d + 3];
    }
    z += __shfl_xor(z, 1, 64);
    z += __shfl_xor(z, 2, 64);
    if (j == 0) {
      float y = fast_tanh(z + b2v);
      float res = __builtin_amdgcn_rcpf(1.0f + __expf(-y));
      long long eo = t * 16 + e4;
      if (xf32) ((float*)outv)[eo] = res;
      else      ((bf16*)outv)[eo] = f2b(res);
    }
    ib = ic;
    uvA = uvB;
  }
}

extern "C" void kernel_launch(void* const* d_in, const int* in_sizes, int n_in,
                              void* d_out, int out_size, void* d_ws, size_t ws_size,
                              hipStream_t stream)
{
  const void* x  = d_in[0];
  const void* ei = d_in[1];
  const void* Wl = d_in[2];
  const void* Wr = d_in[3];
  const void* bl = d_in[4];
  const void* W1 = d_in[5];
  const void* b1 = d_in[6];
  const void* W2 = d_in[7];
  const void* b2 = d_in[8];

  char* ws = (char*)d_ws;
  // layout: pa[0,6.4M) icnt[6.4M,6.8M) flags[6.8M,+128) penc[6800128,+6.4M)
  //         U8[13200128,+6.4M) V8[19600128,+6.4M)
  u64*  pa    = (u64*)ws;
  int*  icnt  = (int*)(ws + 6400000);
  int*  flags = (int*)(ws + 6800000);
  u64*  penc  = (u64*)(ws + 6800128);
  unsigned char* U8 = (unsigned char*)(ws + 13200128);
  unsigned char* V8 = (unsigned char*)(ws + 19600128);

  k_detect<<<1, 64, 0, stream>>>(x, ei, flags);
  hipMemsetAsync(pa, 0, 6800000, stream);

  k_prep<<<(NN * 8) / 256, 256, 0, stream>>>(x, penc, flags);
  k_agg<<<(NE * 8) / 256, 256, 0, stream>>>(penc, ei, pa, icnt, flags);
  k_node_uv<<<512, 256, 0, stream>>>(x, pa, icnt, Wl, Wr, bl, W1, b1, U8, V8, flags);
  k_edge2<<<2048, 256, 0, stream>>>(U8, V8, ei, W2, b2, d_out, flags);
}